// Round 8
// baseline (97.752 us; speedup 1.0000x reference)
//
#include <hip/hip_runtime.h>
#include <hip/hip_fp16.h>

#define NREZ 256
#define NB 8
#define NA 180

// guarded interleaved source: 258x258 pixels of 16B (8 x fp16), 1-px zero border
#define GW 258
#define GBYTES ((size_t)GW * GW * 16)  /* 1,065,024 B */

// LDS tile: 37 rows x 44-pixel stride; row r shifted by q[r&7] pixels.
// LW=44 (=4 mod 8): bank group = (4r + q[r&7] + dx) & 7 = p[r&7] + dx with
// p = {0,2,5,7,1,3,4,6}  ->  q = {0,6,5,3,1,7,4,2} (max 7; 37+7=44 fits LW)
#define LW 44
#define LH 37
#define QTAB 0x24713560u          /* nibble i = q[i] */
#define QPTAB 0x0224477113355660ull /* byte i = q[i] | q[(i+1)&7]<<4 */
#define CHUNK_T 16
#define NCHUNK (NREZ / CHUNK_T)

__device__ __forceinline__ __half2 bc_h2(unsigned int v) {
    return __builtin_bit_cast(__half2, v);
}

__device__ __forceinline__ void dma16(const uint4* g, uint4* l) {
    __builtin_amdgcn_global_load_lds(
        (const __attribute__((address_space(1))) void*)g,
        (__attribute__((address_space(3))) void*)l, 16, 0, 0);
}

// interleave 8 batches -> fp16 uint4 pixel at guard offset (+1,+1); border -> 0
__global__ __launch_bounds__(256) void build_fp16g(const float* __restrict__ img,
                                                   uint4* __restrict__ gbuf) {
    const int gy = blockIdx.x;  // 0..257
    for (int gx = threadIdx.x; gx < GW; gx += 256) {
        uint4 v = make_uint4(0u, 0u, 0u, 0u);
        const int x = gx - 1, y = gy - 1;
        if (x >= 0 && x < NREZ && y >= 0 && y < NREZ) {
            const int p = (y << 8) + x;
            unsigned short h[NB];
#pragma unroll
            for (int b = 0; b < NB; ++b)
                h[b] = __half_as_ushort(__float2half_rn(img[b * (NREZ * NREZ) + p]));
            v.x = (unsigned)h[0] | ((unsigned)h[1] << 16);
            v.y = (unsigned)h[2] | ((unsigned)h[3] << 16);
            v.z = (unsigned)h[4] | ((unsigned)h[5] << 16);
            v.w = (unsigned)h[6] | ((unsigned)h[7] << 16);
        }
        gbuf[(size_t)gy * GW + gx] = v;
    }
}

__global__ __launch_bounds__(256) void radon_dma(const uint4* __restrict__ gbuf,
                                                 const float* __restrict__ angles,
                                                 float* __restrict__ out) {
    __shared__ uint4 tile[LW * LH];  // 26,048 B -> 6 blocks/CU (24 waves)

    const int a = blockIdx.x;
    const int tid = threadIdx.x;
    const int wave = tid >> 6;
    const int lane = tid & 63;
    const int s_sub = lane & 7;
    const int t_sub = lane >> 3;
    const int sIdx = blockIdx.y * 32 + wave * 8 + s_sub;

    const float C = 127.5f;
    float sn, cs;
    sincosf(angles[a], &sn, &cs);
    const float s = (float)sIdx - C;
    const float xs = fmaf(s, cs, C);  // x = fmaf(tt,-sn,xs)
    const float ys = fmaf(s, sn, C);  // y = fmaf(tt, cs,ys)

    // block-uniform s extremes; SAME fmaf chain as per-lane math (fp-monotone)
    const float s_lo = (float)(blockIdx.y * 32) - C;
    const float s_hi = s_lo + 31.f;
    const float xsl = fmaf(s_lo, cs, C), xsh = fmaf(s_hi, cs, C);
    const float ysl = fmaf(s_lo, sn, C), ysh = fmaf(s_hi, sn, C);

    // bbox of chunk ck. Span <= 31|cs|+15|sn| <= 34.45 -> corner offset <= 36
    // -> 37 staged rows/cols always suffice with clamp hi = 220 (220+36 = 256 = guard).
    auto window = [&](int ck, int& bxs, int& bys, bool& interior) {
        const float t_lo = (float)(ck * CHUNK_T) - C;
        const float t_hi = t_lo + 15.f;
        const float x00 = fmaf(t_lo, -sn, xsl), x01 = fmaf(t_hi, -sn, xsl);
        const float x10 = fmaf(t_lo, -sn, xsh), x11 = fmaf(t_hi, -sn, xsh);
        const float y00 = fmaf(t_lo, cs, ysl), y01 = fmaf(t_hi, cs, ysl);
        const float y10 = fmaf(t_lo, cs, ysh), y11 = fmaf(t_hi, cs, ysh);
        const int bx = (int)floorf(fminf(fminf(x00, x01), fminf(x10, x11)));
        const int by = (int)floorf(fminf(fminf(y00, y01), fminf(y10, y11)));
        bxs = min(max(bx, -1), 220);
        bys = min(max(by, -1), 220);
        interior = (bx >= 0) && (by >= 0) && (bx <= 219) && (by <= 219);
    };

    // stage 37 rows x 37 cols; gy,gx in [-1,256] by construction (no bounds checks)
    auto stage = [&](int bxs, int bys) {
#pragma unroll
        for (int k = 0; k < 10; ++k) {
            const int row = wave + 4 * k;  // 0..39
            if (row < LH && lane < 37) {
                const unsigned qr = (QTAB >> ((row & 7) << 2)) & 7u;
                const uint4* gp = gbuf + (size_t)(bys + row + 1) * GW + (bxs + 1) + lane;
                dma16(gp, &tile[row * LW + qr]);
            }
        }
    };

    float accf[NB];
#pragma unroll
    for (int b = 0; b < NB; ++b) accf[b] = 0.f;
    const __half2 hz = __float2half2_rn(0.f);

    int bxs, bys;
    bool interior;
    window(0, bxs, bys, interior);
    stage(bxs, bys);

    for (int ck = 0; ck < NCHUNK; ++ck) {
        __syncthreads();  // DMA of chunk ck drained

        const float t_lo = (float)(ck * CHUNK_T) - C;
        __half2 acc01 = hz, acc23 = hz, acc45 = hz, acc67 = hz;

        auto samp = [&](float tt, bool chk) {
            const float x = fmaf(tt, -sn, xs);
            const float y = fmaf(tt, cs, ys);
            const float xf = floorf(x), yf = floorf(y);
            const int u0 = (int)xf, v0 = (int)yf;
            if (!chk || (u0 >= -1 && u0 <= 255 && v0 >= -1 && v0 <= 255)) {
                const float wu = x - xf, wv = y - yf;
                const float au = 1.f - wu, av = 1.f - wv;
                const __half2 w00 = __float2half2_rn(au * av);
                const __half2 w10 = __float2half2_rn(wu * av);
                const __half2 w01 = __float2half2_rn(au * wv);
                const __half2 w11 = __float2half2_rn(wu * wv);
                const int dx = u0 - bxs;  // in [0, 36]
                const int r = v0 - bys;   // in [0, 35]
                const unsigned pp = (unsigned)(QPTAB >> ((r & 7) << 3));
                const int b00 = r * LW + (int)(pp & 7u) + dx;
                const int b10 = (r + 1) * LW + (int)((pp >> 4) & 7u) + dx;
                const uint4 p00 = tile[b00];
                const uint4 p10 = tile[b00 + 1];
                const uint4 p01 = tile[b10];
                const uint4 p11 = tile[b10 + 1];
                acc01 = __hfma2(w00, bc_h2(p00.x), acc01);
                acc01 = __hfma2(w10, bc_h2(p10.x), acc01);
                acc01 = __hfma2(w01, bc_h2(p01.x), acc01);
                acc01 = __hfma2(w11, bc_h2(p11.x), acc01);
                acc23 = __hfma2(w00, bc_h2(p00.y), acc23);
                acc23 = __hfma2(w10, bc_h2(p10.y), acc23);
                acc23 = __hfma2(w01, bc_h2(p01.y), acc23);
                acc23 = __hfma2(w11, bc_h2(p11.y), acc23);
                acc45 = __hfma2(w00, bc_h2(p00.z), acc45);
                acc45 = __hfma2(w10, bc_h2(p10.z), acc45);
                acc45 = __hfma2(w01, bc_h2(p01.z), acc45);
                acc45 = __hfma2(w11, bc_h2(p11.z), acc45);
                acc67 = __hfma2(w00, bc_h2(p00.w), acc67);
                acc67 = __hfma2(w10, bc_h2(p10.w), acc67);
                acc67 = __hfma2(w01, bc_h2(p01.w), acc67);
                acc67 = __hfma2(w11, bc_h2(p11.w), acc67);
            }
        };

        if (interior) {
            samp(t_lo + (float)t_sub, false);
            samp(t_lo + (float)(t_sub + 8), false);
        } else {
            samp(t_lo + (float)t_sub, true);
            samp(t_lo + (float)(t_sub + 8), true);
        }

        accf[0] += __low2float(acc01); accf[1] += __high2float(acc01);
        accf[2] += __low2float(acc23); accf[3] += __high2float(acc23);
        accf[4] += __low2float(acc45); accf[5] += __high2float(acc45);
        accf[6] += __low2float(acc67); accf[7] += __high2float(acc67);

        __syncthreads();  // all reads of chunk ck done; safe to overwrite tile

        if (ck + 1 < NCHUNK) {
            window(ck + 1, bxs, bys, interior);
            stage(bxs, bys);
        }
    }

#pragma unroll
    for (int b = 0; b < NB; ++b) {
        float v = accf[b];
        v += __shfl_xor(v, 8);
        v += __shfl_xor(v, 16);
        v += __shfl_xor(v, 32);
        accf[b] = v;
    }
    if (t_sub == 0) {
#pragma unroll
        for (int b = 0; b < NB; ++b) {
            out[(b * NA + a) * NREZ + sIdx] = accf[b];
        }
    }
}

// -------- fallback (ws too small): direct fp32 gather with clamps --------
__global__ __launch_bounds__(256) void radon_plain(const float* __restrict__ img,
                                                   const float* __restrict__ angles,
                                                   float* __restrict__ out) {
    const int a = blockIdx.x;
    const int tid = threadIdx.x;
    const int wave = tid >> 6;
    const int lane = tid & 63;
    const int s_sub = lane & 7;
    const int t_sub = lane >> 3;
    const int sIdx = blockIdx.y * 32 + wave * 8 + s_sub;
    const float c = 127.5f;
    float sn, cs;
    sincosf(angles[a], &sn, &cs);
    const float s = (float)sIdx - c;
    float acc[NB];
#pragma unroll
    for (int b = 0; b < NB; ++b) acc[b] = 0.f;
    for (int j = 0; j < NREZ / 8; ++j) {
        const float tt = (float)(t_sub + 8 * j) - c;
        const float x = s * cs - tt * sn + c;
        const float y = s * sn + tt * cs + c;
        const float xf = floorf(x), yf = floorf(y);
        const int u0 = (int)xf, v0 = (int)yf;
        if (u0 < -1 || u0 >= NREZ || v0 < -1 || v0 >= NREZ) continue;
        const float wu = x - xf, wv = y - yf;
        const bool iu0 = (u0 >= 0), iu1 = (u0 + 1 <= NREZ - 1);
        const bool iv0 = (v0 >= 0), iv1 = (v0 + 1 <= NREZ - 1);
        const float w00 = (1.f - wu) * (1.f - wv) * ((iu0 && iv0) ? 1.f : 0.f);
        const float w10 = wu * (1.f - wv) * ((iu1 && iv0) ? 1.f : 0.f);
        const float w01 = (1.f - wu) * wv * ((iu0 && iv1) ? 1.f : 0.f);
        const float w11 = wu * wv * ((iu1 && iv1) ? 1.f : 0.f);
        const int u0c = min(max(u0, 0), NREZ - 1);
        const int u1c = min(u0 + 1, NREZ - 1);
        const int v0c = min(max(v0, 0), NREZ - 1);
        const int v1c = min(v0 + 1, NREZ - 1);
#pragma unroll
        for (int b = 0; b < NB; ++b) {
            const float* p = img + b * (NREZ * NREZ);
            acc[b] += w00 * p[v0c * NREZ + u0c] + w10 * p[v0c * NREZ + u1c] +
                      w01 * p[v1c * NREZ + u0c] + w11 * p[v1c * NREZ + u1c];
        }
    }
#pragma unroll
    for (int b = 0; b < NB; ++b) {
        float v = acc[b];
        v += __shfl_xor(v, 8);
        v += __shfl_xor(v, 16);
        v += __shfl_xor(v, 32);
        acc[b] = v;
    }
    if (t_sub == 0) {
#pragma unroll
        for (int b = 0; b < NB; ++b) out[(b * NA + a) * NREZ + sIdx] = acc[b];
    }
}

extern "C" void kernel_launch(void* const* d_in, const int* in_sizes, int n_in,
                              void* d_out, int out_size, void* d_ws, size_t ws_size,
                              hipStream_t stream) {
    (void)in_sizes; (void)n_in; (void)out_size;
    const float* imgs = (const float*)d_in[0];
    const float* angles = (const float*)d_in[1];
    float* out = (float*)d_out;

    dim3 grid(NA, NREZ / 32);
    if (ws_size >= GBYTES) {
        uint4* gbuf = (uint4*)d_ws;
        build_fp16g<<<GW, 256, 0, stream>>>(imgs, gbuf);  // fused guard-zeroing
        radon_dma<<<grid, 256, 0, stream>>>(gbuf, angles, out);
    } else {
        radon_plain<<<grid, 256, 0, stream>>>(imgs, angles, out);
    }
}

// Round 9
// 90.850 us; speedup vs baseline: 1.0760x; 1.0760x over previous
//
#include <hip/hip_runtime.h>
#include <hip/hip_fp16.h>

#define NREZ 256
#define NB 8
#define NA 180

// guarded interleaved source: 258x258 pixels of 16B (8 x fp16), 1-px zero border
#define GW 258
#define GBYTES ((size_t)GW * GW * 16)  /* 1,065,024 B */

// LDS tile: 47 rows x 47-pixel stride, no swizzle. 47 % 8 == 7: with 32s x 2t
// lane order, theta=0 and theta=90 give exactly 8 lanes/bank-group (conflict-free);
// generic angles near-uniform.
#define LW 47
#define LH 47
#define CHUNK_T 32
#define NCHUNK (NREZ / CHUNK_T)

__device__ __forceinline__ __half2 bc_h2(unsigned int v) {
    return __builtin_bit_cast(__half2, v);
}

__device__ __forceinline__ void dma16(const uint4* g, uint4* l) {
    // dest is wave-uniform base; HW scatters lane i to base + i*16 (verified R6-R8)
    __builtin_amdgcn_global_load_lds(
        (const __attribute__((address_space(1))) void*)g,
        (__attribute__((address_space(3))) void*)l, 16, 0, 0);
}

// interleave 8 batches -> fp16 uint4 pixel at guard offset (+1,+1); border -> 0
__global__ __launch_bounds__(256) void build_fp16g(const float* __restrict__ img,
                                                   uint4* __restrict__ gbuf) {
    const int gy = blockIdx.x;  // 0..257
    for (int gx = threadIdx.x; gx < GW; gx += 256) {
        uint4 v = make_uint4(0u, 0u, 0u, 0u);
        const int x = gx - 1, y = gy - 1;
        if (x >= 0 && x < NREZ && y >= 0 && y < NREZ) {
            const int p = (y << 8) + x;
            unsigned short h[NB];
#pragma unroll
            for (int b = 0; b < NB; ++b)
                h[b] = __half_as_ushort(__float2half_rn(img[b * (NREZ * NREZ) + p]));
            v.x = (unsigned)h[0] | ((unsigned)h[1] << 16);
            v.y = (unsigned)h[2] | ((unsigned)h[3] << 16);
            v.z = (unsigned)h[4] | ((unsigned)h[5] << 16);
            v.w = (unsigned)h[6] | ((unsigned)h[7] << 16);
        }
        gbuf[(size_t)gy * GW + gx] = v;
    }
}

__global__ __launch_bounds__(256, 4) void radon_dma(const uint4* __restrict__ gbuf,
                                                    const float* __restrict__ angles,
                                                    float* __restrict__ out) {
    __shared__ uint4 tile[LW * LH];  // 35,344 B -> 4 blocks/CU (16 waves)

    const int a = blockIdx.x;
    const int tid = threadIdx.x;
    const int wave = tid >> 6;
    const int lane = tid & 63;
    const int ls = lane & 31;   // s within the block's 32-s strip
    const int lp = lane >> 5;   // t phase (0/1)
    const int sIdx = blockIdx.y * 32 + ls;
    const int tw = 2 * wave + lp;  // wave+phase t-offset: 0..7

    const float C = 127.5f;
    float sn, cs;
    sincosf(angles[a], &sn, &cs);
    const float s = (float)sIdx - C;
    const float xs = fmaf(s, cs, C);  // x = fmaf(tt,-sn,xs)  (xs in [0,255])
    const float ys = fmaf(s, sn, C);  // y = fmaf(tt, cs,ys)

    // block-uniform s extremes; SAME fmaf chain as per-lane math (fp-monotone)
    const float s_lo = (float)(blockIdx.y * 32) - C;
    const float s_hi = s_lo + 31.f;
    const float xsl = fmaf(s_lo, cs, C), xsh = fmaf(s_hi, cs, C);
    const float ysl = fmaf(s_lo, sn, C), ysh = fmaf(s_hi, sn, C);

    // bbox of chunk ck: corner span <= 31(|cs|+|sn|) <= 43.9 -> u0,v0 in [b?, b?+44],
    // +1 corner -> 46 px; 47 staged cols/rows cover all cases incl. right-edge clamp
    // (bxs=210: dx = u0-210 <= 45, dx+1 = 46 <= 46). gx = bxs+1+lane <= 210+1+46 = 257 ok.
    auto window = [&](int ck, int& bxs, int& bys, bool& interior) {
        const float t_lo = (float)(ck * CHUNK_T) - C;
        const float t_hi = t_lo + 31.f;
        const float x00 = fmaf(t_lo, -sn, xsl), x01 = fmaf(t_hi, -sn, xsl);
        const float x10 = fmaf(t_lo, -sn, xsh), x11 = fmaf(t_hi, -sn, xsh);
        const float y00 = fmaf(t_lo, cs, ysl), y01 = fmaf(t_hi, cs, ysl);
        const float y10 = fmaf(t_lo, cs, ysh), y11 = fmaf(t_hi, cs, ysh);
        const int bx = (int)floorf(fminf(fminf(x00, x01), fminf(x10, x11)));
        const int by = (int)floorf(fminf(fminf(y00, y01), fminf(y10, y11)));
        bxs = min(max(bx, -1), 210);
        bys = min(max(by, -1), 210);
        // no clamp took effect AND u0+1 <= bx+45 <= 255, v likewise -> no OOB samples
        interior = (bx >= 0) && (by >= 0) && (bx <= 210) && (by <= 210);
    };

    // stage 47 rows x 47 cols; gx,gy in [0,257] of padded source by construction
    auto stage = [&](int bxs, int bys) {
#pragma unroll
        for (int k = 0; k < 12; ++k) {
            const int row = wave + 4 * k;  // 0..47
            if (row < LH && lane < LW) {
                const uint4* gp = gbuf + (size_t)(bys + row + 1) * GW + (bxs + 1) + lane;
                dma16(gp, &tile[row * LW]);
            }
        }
    };

    float accf[NB];
#pragma unroll
    for (int b = 0; b < NB; ++b) accf[b] = 0.f;
    const __half2 hz = __float2half2_rn(0.f);

    int bxs, bys;
    bool interior;
    window(0, bxs, bys, interior);
    stage(bxs, bys);

    for (int ck = 0; ck < NCHUNK; ++ck) {
        __syncthreads();  // DMA of chunk ck drained

        const float t_lo = (float)(ck * CHUNK_T) - C;
        __half2 acc01 = hz, acc23 = hz, acc45 = hz, acc67 = hz;

        auto samp = [&](float tt, bool chk) {
            const float x = fmaf(tt, -sn, xs);
            const float y = fmaf(tt, cs, ys);
            const float xf = floorf(x), yf = floorf(y);
            const int u0 = (int)xf, v0 = (int)yf;
            if (!chk || (u0 >= -1 && u0 <= 255 && v0 >= -1 && v0 <= 255)) {
                const float wu = x - xf, wv = y - yf;
                const float au = 1.f - wu, av = 1.f - wv;
                const __half2 w00 = __float2half2_rn(au * av);
                const __half2 w10 = __float2half2_rn(wu * av);
                const __half2 w01 = __float2half2_rn(au * wv);
                const __half2 w11 = __float2half2_rn(wu * wv);
                const int dx = u0 - bxs;  // in [0, 45]
                const int r = v0 - bys;   // in [0, 45]
                const int b00 = r * LW + dx;
                const int b10 = b00 + LW;
                const uint4 p00 = tile[b00];
                const uint4 p10 = tile[b00 + 1];
                const uint4 p01 = tile[b10];
                const uint4 p11 = tile[b10 + 1];
                acc01 = __hfma2(w00, bc_h2(p00.x), acc01);
                acc01 = __hfma2(w10, bc_h2(p10.x), acc01);
                acc01 = __hfma2(w01, bc_h2(p01.x), acc01);
                acc01 = __hfma2(w11, bc_h2(p11.x), acc01);
                acc23 = __hfma2(w00, bc_h2(p00.y), acc23);
                acc23 = __hfma2(w10, bc_h2(p10.y), acc23);
                acc23 = __hfma2(w01, bc_h2(p01.y), acc23);
                acc23 = __hfma2(w11, bc_h2(p11.y), acc23);
                acc45 = __hfma2(w00, bc_h2(p00.z), acc45);
                acc45 = __hfma2(w10, bc_h2(p10.z), acc45);
                acc45 = __hfma2(w01, bc_h2(p01.z), acc45);
                acc45 = __hfma2(w11, bc_h2(p11.z), acc45);
                acc67 = __hfma2(w00, bc_h2(p00.w), acc67);
                acc67 = __hfma2(w10, bc_h2(p10.w), acc67);
                acc67 = __hfma2(w01, bc_h2(p01.w), acc67);
                acc67 = __hfma2(w11, bc_h2(p11.w), acc67);
            }
        };

        if (interior) {
#pragma unroll
            for (int it = 0; it < 4; ++it)
                samp(t_lo + (float)(tw + 8 * it), false);
        } else {
#pragma unroll
            for (int it = 0; it < 4; ++it)
                samp(t_lo + (float)(tw + 8 * it), true);
        }

        accf[0] += __low2float(acc01); accf[1] += __high2float(acc01);
        accf[2] += __low2float(acc23); accf[3] += __high2float(acc23);
        accf[4] += __low2float(acc45); accf[5] += __high2float(acc45);
        accf[6] += __low2float(acc67); accf[7] += __high2float(acc67);

        __syncthreads();  // all reads of chunk ck done; safe to overwrite tile

        if (ck + 1 < NCHUNK) {
            window(ck + 1, bxs, bys, interior);
            stage(bxs, bys);
        }
    }

    // ---- reduction: t-phase pair within wave, then 4 waves via LDS ----
#pragma unroll
    for (int b = 0; b < NB; ++b) accf[b] += __shfl_xor(accf[b], 32);

    float4* red4 = (float4*)tile;  // 4 waves x 32 s x 8 b = 4 KB, tile is free
    if (lane < 32) {
        red4[(wave * 32 + lane) * 2 + 0] = make_float4(accf[0], accf[1], accf[2], accf[3]);
        red4[(wave * 32 + lane) * 2 + 1] = make_float4(accf[4], accf[5], accf[6], accf[7]);
    }
    __syncthreads();
    {
        const float* red = (const float*)tile;
        const int b = tid >> 5;   // 0..7
        const int ss = tid & 31;  // 0..31
        const int base = ss * 8 + b;
        const float sum = red[base] + red[256 + base] + red[512 + base] + red[768 + base];
        out[(b * NA + a) * NREZ + blockIdx.y * 32 + ss] = sum;
    }
}

// -------- fallback (ws too small): direct fp32 gather with clamps --------
__global__ __launch_bounds__(256) void radon_plain(const float* __restrict__ img,
                                                   const float* __restrict__ angles,
                                                   float* __restrict__ out) {
    const int a = blockIdx.x;
    const int tid = threadIdx.x;
    const int wave = tid >> 6;
    const int lane = tid & 63;
    const int s_sub = lane & 7;
    const int t_sub = lane >> 3;
    const int sIdx = blockIdx.y * 32 + wave * 8 + s_sub;
    const float c = 127.5f;
    float sn, cs;
    sincosf(angles[a], &sn, &cs);
    const float s = (float)sIdx - c;
    float acc[NB];
#pragma unroll
    for (int b = 0; b < NB; ++b) acc[b] = 0.f;
    for (int j = 0; j < NREZ / 8; ++j) {
        const float tt = (float)(t_sub + 8 * j) - c;
        const float x = s * cs - tt * sn + c;
        const float y = s * sn + tt * cs + c;
        const float xf = floorf(x), yf = floorf(y);
        const int u0 = (int)xf, v0 = (int)yf;
        if (u0 < -1 || u0 >= NREZ || v0 < -1 || v0 >= NREZ) continue;
        const float wu = x - xf, wv = y - yf;
        const bool iu0 = (u0 >= 0), iu1 = (u0 + 1 <= NREZ - 1);
        const bool iv0 = (v0 >= 0), iv1 = (v0 + 1 <= NREZ - 1);
        const float w00 = (1.f - wu) * (1.f - wv) * ((iu0 && iv0) ? 1.f : 0.f);
        const float w10 = wu * (1.f - wv) * ((iu1 && iv0) ? 1.f : 0.f);
        const float w01 = (1.f - wu) * wv * ((iu0 && iv1) ? 1.f : 0.f);
        const float w11 = wu * wv * ((iu1 && iv1) ? 1.f : 0.f);
        const int u0c = min(max(u0, 0), NREZ - 1);
        const int u1c = min(u0 + 1, NREZ - 1);
        const int v0c = min(max(v0, 0), NREZ - 1);
        const int v1c = min(v0 + 1, NREZ - 1);
#pragma unroll
        for (int b = 0; b < NB; ++b) {
            const float* p = img + b * (NREZ * NREZ);
            acc[b] += w00 * p[v0c * NREZ + u0c] + w10 * p[v0c * NREZ + u1c] +
                      w01 * p[v1c * NREZ + u0c] + w11 * p[v1c * NREZ + u1c];
        }
    }
#pragma unroll
    for (int b = 0; b < NB; ++b) {
        float v = acc[b];
        v += __shfl_xor(v, 8);
        v += __shfl_xor(v, 16);
        v += __shfl_xor(v, 32);
        acc[b] = v;
    }
    if (t_sub == 0) {
#pragma unroll
        for (int b = 0; b < NB; ++b) out[(b * NA + a) * NREZ + sIdx] = acc[b];
    }
}

extern "C" void kernel_launch(void* const* d_in, const int* in_sizes, int n_in,
                              void* d_out, int out_size, void* d_ws, size_t ws_size,
                              hipStream_t stream) {
    (void)in_sizes; (void)n_in; (void)out_size;
    const float* imgs = (const float*)d_in[0];
    const float* angles = (const float*)d_in[1];
    float* out = (float*)d_out;

    dim3 grid(NA, NREZ / 32);
    if (ws_size >= GBYTES) {
        uint4* gbuf = (uint4*)d_ws;
        build_fp16g<<<GW, 256, 0, stream>>>(imgs, gbuf);  // fused guard-zeroing
        radon_dma<<<grid, 256, 0, stream>>>(gbuf, angles, out);
    } else {
        radon_plain<<<grid, 256, 0, stream>>>(imgs, angles, out);
    }
}

// Round 10
// 90.208 us; speedup vs baseline: 1.0836x; 1.0071x over previous
//
#include <hip/hip_runtime.h>
#include <hip/hip_fp16.h>

#define NREZ 256
#define NB 8
#define NA 180

// guarded interleaved source: 258x258 pixels of 16B (8 x fp16), 1-px zero border
#define GW 258
#define GBYTES ((size_t)GW * GW * 16)  /* 1,065,024 B */

// LDS tile: 47 rows x LWr-pixel stride, LWr chosen PER ANGLE from [47,52] so the
// per-lane address step sigma = sn*LWr + cs (pixels, 16B) is far from even mod 2
// -> 32 linear-stepping lanes spread ~uniformly over the 8 bank groups.
#define LWMAX 52
#define LH 47
#define CHUNK_T 32
#define NCHUNK (NREZ / CHUNK_T)

__device__ __forceinline__ __half2 bc_h2(unsigned int v) {
    return __builtin_bit_cast(__half2, v);
}

__device__ __forceinline__ void dma16(const uint4* g, uint4* l) {
    // dest is wave-uniform base; HW scatters lane i to base + i*16 (verified R6-R9)
    __builtin_amdgcn_global_load_lds(
        (const __attribute__((address_space(1))) void*)g,
        (__attribute__((address_space(3))) void*)l, 16, 0, 0);
}

// interleave 8 batches -> fp16 uint4 pixel at guard offset (+1,+1); border -> 0
__global__ __launch_bounds__(256) void build_fp16g(const float* __restrict__ img,
                                                   uint4* __restrict__ gbuf) {
    const int gy = blockIdx.x;  // 0..257
    for (int gx = threadIdx.x; gx < GW; gx += 256) {
        uint4 v = make_uint4(0u, 0u, 0u, 0u);
        const int x = gx - 1, y = gy - 1;
        if (x >= 0 && x < NREZ && y >= 0 && y < NREZ) {
            const int p = (y << 8) + x;
            unsigned short h[NB];
#pragma unroll
            for (int b = 0; b < NB; ++b)
                h[b] = __half_as_ushort(__float2half_rn(img[b * (NREZ * NREZ) + p]));
            v.x = (unsigned)h[0] | ((unsigned)h[1] << 16);
            v.y = (unsigned)h[2] | ((unsigned)h[3] << 16);
            v.z = (unsigned)h[4] | ((unsigned)h[5] << 16);
            v.w = (unsigned)h[6] | ((unsigned)h[7] << 16);
        }
        gbuf[(size_t)gy * GW + gx] = v;
    }
}

__global__ __launch_bounds__(256, 4) void radon_dma(const uint4* __restrict__ gbuf,
                                                    const float* __restrict__ angles,
                                                    float* __restrict__ out) {
    __shared__ uint4 tile[LWMAX * LH];  // 39,104 B -> 4 blocks/CU (16 waves)

    const int a = blockIdx.x;
    const int tid = threadIdx.x;
    const int wave = tid >> 6;
    const int lane = tid & 63;
    const int ls = lane & 31;   // s within the block's 32-s strip
    const int lp = lane >> 5;   // t phase (0/1)
    const int sIdx = blockIdx.y * 32 + ls;
    const int tw = 2 * wave + lp;  // wave+phase t-offset: 0..7

    const float C = 127.5f;
    float sn, cs;
    sincosf(angles[a], &sn, &cs);

    // per-angle row stride: maximize margin of (sn*LW + cs) mod 2 from even
    int LWr = 47;
    {
        float best = -1.f;
#pragma unroll
        for (int w = 47; w <= LWMAX; ++w) {
            const float sig = fmaf(sn, (float)w, cs);
            const float u = sig - 2.f * floorf(sig * 0.5f);  // [0,2)
            const float m = 1.f - fabsf(u - 1.f);            // 1 = odd (perfect)
            if (m > best) { best = m; LWr = w; }
        }
    }

    const float s = (float)sIdx - C;
    const float xs = fmaf(s, cs, C);  // x = fmaf(tt,-sn,xs)
    const float ys = fmaf(s, sn, C);  // y = fmaf(tt, cs,ys)

    // block-uniform s extremes; SAME fmaf chain as per-lane math (fp-monotone)
    const float s_lo = (float)(blockIdx.y * 32) - C;
    const float s_hi = s_lo + 31.f;
    const float xsl = fmaf(s_lo, cs, C), xsh = fmaf(s_hi, cs, C);
    const float ysl = fmaf(s_lo, sn, C), ysh = fmaf(s_hi, sn, C);

    // bbox of chunk ck: corner span <= 31(|cs|+|sn|) <= 43.9 -> u0,v0 in [b?, b?+44],
    // +1 corner -> 46 px; 47 staged cols/rows cover all cases incl. right-edge clamp
    // (bxs=210: dx = u0-210 <= 45, dx+1 = 46). gx = bxs+1+lane <= 210+1+46 = 257 ok.
    auto window = [&](int ck, int& bxs, int& bys, bool& interior) {
        const float t_lo = (float)(ck * CHUNK_T) - C;
        const float t_hi = t_lo + 31.f;
        const float x00 = fmaf(t_lo, -sn, xsl), x01 = fmaf(t_hi, -sn, xsl);
        const float x10 = fmaf(t_lo, -sn, xsh), x11 = fmaf(t_hi, -sn, xsh);
        const float y00 = fmaf(t_lo, cs, ysl), y01 = fmaf(t_hi, cs, ysl);
        const float y10 = fmaf(t_lo, cs, ysh), y11 = fmaf(t_hi, cs, ysh);
        const int bx = (int)floorf(fminf(fminf(x00, x01), fminf(x10, x11)));
        const int by = (int)floorf(fminf(fminf(y00, y01), fminf(y10, y11)));
        bxs = min(max(bx, -1), 210);
        bys = min(max(by, -1), 210);
        interior = (bx >= 0) && (by >= 0) && (bx <= 210) && (by <= 210);
    };

    // stage 47 rows x 47 cols; gx,gy in [0,257] of padded source by construction
    auto stage = [&](int bxs, int bys) {
#pragma unroll
        for (int k = 0; k < 12; ++k) {
            const int row = wave + 4 * k;  // 0..47
            if (row < LH && lane < 47) {
                const uint4* gp = gbuf + (size_t)(bys + row + 1) * GW + (bxs + 1) + lane;
                dma16(gp, &tile[row * LWr]);
            }
        }
    };

    float accf[NB];
#pragma unroll
    for (int b = 0; b < NB; ++b) accf[b] = 0.f;
    const __half2 hz = __float2half2_rn(0.f);

    int bxs, bys;
    bool interior;
    window(0, bxs, bys, interior);
    stage(bxs, bys);

    for (int ck = 0; ck < NCHUNK; ++ck) {
        __syncthreads();  // DMA of chunk ck drained

        const float t_lo = (float)(ck * CHUNK_T) - C;
        __half2 acc01 = hz, acc23 = hz, acc45 = hz, acc67 = hz;

        auto samp = [&](float tt, bool chk) {
            const float x = fmaf(tt, -sn, xs);
            const float y = fmaf(tt, cs, ys);
            const float xf = floorf(x), yf = floorf(y);
            const int u0 = (int)xf, v0 = (int)yf;
            if (!chk || (u0 >= -1 && u0 <= 255 && v0 >= -1 && v0 <= 255)) {
                const float wu = x - xf, wv = y - yf;
                const float au = 1.f - wu, av = 1.f - wv;
                const __half2 w00 = __float2half2_rn(au * av);
                const __half2 w10 = __float2half2_rn(wu * av);
                const __half2 w01 = __float2half2_rn(au * wv);
                const __half2 w11 = __float2half2_rn(wu * wv);
                const int dx = u0 - bxs;  // in [0, 45]
                const int r = v0 - bys;   // in [0, 45]
                const int b00 = r * LWr + dx;
                const int b10 = b00 + LWr;
                const uint4 p00 = tile[b00];
                const uint4 p10 = tile[b00 + 1];
                const uint4 p01 = tile[b10];
                const uint4 p11 = tile[b10 + 1];
                acc01 = __hfma2(w00, bc_h2(p00.x), acc01);
                acc01 = __hfma2(w10, bc_h2(p10.x), acc01);
                acc01 = __hfma2(w01, bc_h2(p01.x), acc01);
                acc01 = __hfma2(w11, bc_h2(p11.x), acc01);
                acc23 = __hfma2(w00, bc_h2(p00.y), acc23);
                acc23 = __hfma2(w10, bc_h2(p10.y), acc23);
                acc23 = __hfma2(w01, bc_h2(p01.y), acc23);
                acc23 = __hfma2(w11, bc_h2(p11.y), acc23);
                acc45 = __hfma2(w00, bc_h2(p00.z), acc45);
                acc45 = __hfma2(w10, bc_h2(p10.z), acc45);
                acc45 = __hfma2(w01, bc_h2(p01.z), acc45);
                acc45 = __hfma2(w11, bc_h2(p11.z), acc45);
                acc67 = __hfma2(w00, bc_h2(p00.w), acc67);
                acc67 = __hfma2(w10, bc_h2(p10.w), acc67);
                acc67 = __hfma2(w01, bc_h2(p01.w), acc67);
                acc67 = __hfma2(w11, bc_h2(p11.w), acc67);
            }
        };

        if (interior) {
#pragma unroll
            for (int it = 0; it < 4; ++it)
                samp(t_lo + (float)(tw + 8 * it), false);
        } else {
#pragma unroll
            for (int it = 0; it < 4; ++it)
                samp(t_lo + (float)(tw + 8 * it), true);
        }

        accf[0] += __low2float(acc01); accf[1] += __high2float(acc01);
        accf[2] += __low2float(acc23); accf[3] += __high2float(acc23);
        accf[4] += __low2float(acc45); accf[5] += __high2float(acc45);
        accf[6] += __low2float(acc67); accf[7] += __high2float(acc67);

        __syncthreads();  // all reads of chunk ck done; safe to overwrite tile

        if (ck + 1 < NCHUNK) {
            window(ck + 1, bxs, bys, interior);
            stage(bxs, bys);
        }
    }

    // ---- reduction: t-phase pair within wave, then 4 waves via LDS ----
#pragma unroll
    for (int b = 0; b < NB; ++b) accf[b] += __shfl_xor(accf[b], 32);

    float4* red4 = (float4*)tile;  // 4 waves x 32 s x 8 b = 4 KB, tile is free
    if (lane < 32) {
        red4[(wave * 32 + lane) * 2 + 0] = make_float4(accf[0], accf[1], accf[2], accf[3]);
        red4[(wave * 32 + lane) * 2 + 1] = make_float4(accf[4], accf[5], accf[6], accf[7]);
    }
    __syncthreads();
    {
        const float* red = (const float*)tile;
        const int b = tid >> 5;   // 0..7
        const int ss = tid & 31;  // 0..31
        const int base = ss * 8 + b;
        const float sum = red[base] + red[256 + base] + red[512 + base] + red[768 + base];
        out[(b * NA + a) * NREZ + blockIdx.y * 32 + ss] = sum;
    }
}

// -------- fallback (ws too small): direct fp32 gather with clamps --------
__global__ __launch_bounds__(256) void radon_plain(const float* __restrict__ img,
                                                   const float* __restrict__ angles,
                                                   float* __restrict__ out) {
    const int a = blockIdx.x;
    const int tid = threadIdx.x;
    const int wave = tid >> 6;
    const int lane = tid & 63;
    const int s_sub = lane & 7;
    const int t_sub = lane >> 3;
    const int sIdx = blockIdx.y * 32 + wave * 8 + s_sub;
    const float c = 127.5f;
    float sn, cs;
    sincosf(angles[a], &sn, &cs);
    const float s = (float)sIdx - c;
    float acc[NB];
#pragma unroll
    for (int b = 0; b < NB; ++b) acc[b] = 0.f;
    for (int j = 0; j < NREZ / 8; ++j) {
        const float tt = (float)(t_sub + 8 * j) - c;
        const float x = s * cs - tt * sn + c;
        const float y = s * sn + tt * cs + c;
        const float xf = floorf(x), yf = floorf(y);
        const int u0 = (int)xf, v0 = (int)yf;
        if (u0 < -1 || u0 >= NREZ || v0 < -1 || v0 >= NREZ) continue;
        const float wu = x - xf, wv = y - yf;
        const bool iu0 = (u0 >= 0), iu1 = (u0 + 1 <= NREZ - 1);
        const bool iv0 = (v0 >= 0), iv1 = (v0 + 1 <= NREZ - 1);
        const float w00 = (1.f - wu) * (1.f - wv) * ((iu0 && iv0) ? 1.f : 0.f);
        const float w10 = wu * (1.f - wv) * ((iu1 && iv0) ? 1.f : 0.f);
        const float w01 = (1.f - wu) * wv * ((iu0 && iv1) ? 1.f : 0.f);
        const float w11 = wu * wv * ((iu1 && iv1) ? 1.f : 0.f);
        const int u0c = min(max(u0, 0), NREZ - 1);
        const int u1c = min(u0 + 1, NREZ - 1);
        const int v0c = min(max(v0, 0), NREZ - 1);
        const int v1c = min(v0 + 1, NREZ - 1);
#pragma unroll
        for (int b = 0; b < NB; ++b) {
            const float* p = img + b * (NREZ * NREZ);
            acc[b] += w00 * p[v0c * NREZ + u0c] + w10 * p[v0c * NREZ + u1c] +
                      w01 * p[v1c * NREZ + u0c] + w11 * p[v1c * NREZ + u1c];
        }
    }
#pragma unroll
    for (int b = 0; b < NB; ++b) {
        float v = acc[b];
        v += __shfl_xor(v, 8);
        v += __shfl_xor(v, 16);
        v += __shfl_xor(v, 32);
        acc[b] = v;
    }
    if (t_sub == 0) {
#pragma unroll
        for (int b = 0; b < NB; ++b) out[(b * NA + a) * NREZ + sIdx] = acc[b];
    }
}

extern "C" void kernel_launch(void* const* d_in, const int* in_sizes, int n_in,
                              void* d_out, int out_size, void* d_ws, size_t ws_size,
                              hipStream_t stream) {
    (void)in_sizes; (void)n_in; (void)out_size;
    const float* imgs = (const float*)d_in[0];
    const float* angles = (const float*)d_in[1];
    float* out = (float*)d_out;

    dim3 grid(NA, NREZ / 32);
    if (ws_size >= GBYTES) {
        uint4* gbuf = (uint4*)d_ws;
        build_fp16g<<<GW, 256, 0, stream>>>(imgs, gbuf);  // fused guard-zeroing
        radon_dma<<<grid, 256, 0, stream>>>(gbuf, angles, out);
    } else {
        radon_plain<<<grid, 256, 0, stream>>>(imgs, angles, out);
    }
}